// Round 7
// baseline (533.068 us; speedup 1.0000x reference)
//
#include <hip/hip_runtime.h>
#include <hip/hip_bf16.h>

// Decoder block: self-MHA -> add+LN -> cross-MHA -> add+LN(resid=orig x) -> FFN -> add+LN
// B=4 S=1024 H=1024 NH=16 d=64.
// R14 = R13 + GEMM MODE0: BK=32 counted-vmcnt(4) double-buffer at 32KB LDS
// (same LDS as the old single-buffer BK=64 -> same occupancy, but no per-iter
// full vmcnt(0) drain) for QKV/cross/FFN1; O-proj/FFN2 also MODE0 with
// split-K=4 (4 blocks/CU, bf16 partials x4, proven in R9/R10). Attention = R13
// (64 q-rows/block, dbuf, mask-in-LDS, XCD-chunked, setprio).

typedef float float4v __attribute__((ext_vector_type(4)));
typedef __bf16 bf16x8 __attribute__((ext_vector_type(8)));
typedef unsigned short ushort8 __attribute__((ext_vector_type(8)));
typedef unsigned int uint2v __attribute__((ext_vector_type(2)));

#define VBIG (1 << 29)

__device__ __forceinline__ unsigned short f2bf1(float f) {
    unsigned u = __builtin_bit_cast(unsigned, f);
    u += 0x7fffu + ((u >> 16) & 1u);
    return (unsigned short)(u >> 16);
}
__device__ __forceinline__ unsigned f2bf2(float lo, float hi) {
    unsigned a = __builtin_bit_cast(unsigned, lo);
    a += 0x7fffu + ((a >> 16) & 1u);
    unsigned b = __builtin_bit_cast(unsigned, hi);
    b += 0x7fffu + ((b >> 16) & 1u);
    return (a >> 16) | (b & 0xffff0000u);
}
__device__ __forceinline__ float4v bf4_to_f4(uint2v u) {
    float4v r;
    r.x = __builtin_bit_cast(float, (u.x & 0xffffu) << 16);
    r.y = __builtin_bit_cast(float, u.x & 0xffff0000u);
    r.z = __builtin_bit_cast(float, (u.y & 0xffffu) << 16);
    r.w = __builtin_bit_cast(float, u.y & 0xffff0000u);
    return r;
}
__device__ __forceinline__ bf16x8 ldsv8(const unsigned short* p) {
    return __builtin_bit_cast(bf16x8, *(const ushort8*)p);
}
// async global->LDS, 16B per lane; LDS dest = wave-uniform base + lane*16
__device__ __forceinline__ void async16(const unsigned short* g, unsigned short* l) {
    __builtin_amdgcn_global_load_lds(
        (const __attribute__((address_space(1))) unsigned int*)(g),
        (__attribute__((address_space(3))) unsigned int*)(l),
        16, 0, 0);
}

// ---------------- GEMM core: C[M,N] = A[M,K] @ Bt[N,K]^T (+ bias) --------------
// 128x128 tile, 4 waves 2x2 of 64x64, 16x16x32 MFMA. bf16 output always.
// MODE 0: BK=32 double-buffered (2x[128][32] per matrix = 32KB total LDS),
//   counted vmcnt(4) -> no mid-loop drain, occupancy = old single-buffer.
//   Swizzle: LDS (row, chunk c) holds global chunk c ^ ((row>>1)&3); read
//   chunk quad ^ ((lr>>1)&3). Quarter-wave bank aliasing 2-way = free.
// MODE 1: BK=64 double-buffered (64KB LDS), counted vmcnt(8) — legacy path.
// vrel >= 0: V^T pos-permuted epilogue into VTout (token t -> (t&~63)+pos(t&63),
// pos(k)=(k&15)*4+(k>>4)); vrel = col offset rel. to V region start.
template <int RELU, int MODE>
__device__ __forceinline__ void gemm_core(
    const unsigned short* __restrict__ A, const unsigned short* __restrict__ Bt,
    const float* __restrict__ bias, unsigned short* __restrict__ Cout,
    int m0, int n0, int K, int KL, int kbase, int ldc,
    float qs, int vrel, unsigned short* __restrict__ VTout, size_t outoff)
{
    constexpr int BUFSZ = MODE ? 8192 : 4096;
    __shared__ __align__(16) unsigned short As[2][BUFSZ];
    __shared__ __align__(16) unsigned short Bs[2][BUFSZ];

    const int tid = threadIdx.x;
    const int w = tid >> 6, lane = tid & 63;
    const int lr = lane & 15, quad = lane >> 4;
    const int wm = (w >> 1) * 64, wn = (w & 1) * 64;

    float4v acc[4][4];
#pragma unroll
    for (int i = 0; i < 4; i++)
#pragma unroll
        for (int j = 0; j < 4; j++) acc[i][j] = 0.f;

    if constexpr (MODE == 0) {
        // ---- BK=32 dbuf ----
        const int sr = lane >> 2, sc = lane & 3;             // 16 rows x 4 chunks
        const int gch = (sc ^ ((lane >> 3) & 3)) * 8;        // pre-swizzled src chunk
        const unsigned short* Ag = A + (size_t)(m0 + w * 16 + sr) * K + kbase + gch;
        const unsigned short* Bg = Bt + (size_t)(n0 + w * 16 + sr) * K + kbase + gch;
        const int ch2 = (quad ^ ((lr >> 1) & 3)) * 8;        // read-side chunk

        auto issue32 = [&](int buf, int k0) {
            unsigned short* Al = &As[buf][(w * 16) * 32];
            unsigned short* Bl = &Bs[buf][(w * 16) * 32];
            async16(Ag + k0, Al);
            async16(Ag + (size_t)64 * K + k0, Al + 64 * 32);
            async16(Bg + k0, Bl);
            async16(Bg + (size_t)64 * K + k0, Bl + 64 * 32);
        };
        auto compute32 = [&](int buf) {
            const unsigned short* Ab = As[buf];
            const unsigned short* Bb = Bs[buf];
            bf16x8 af[4], bf[4];
#pragma unroll
            for (int i = 0; i < 4; i++) {
                af[i] = ldsv8(&Ab[(wm + i * 16 + lr) * 32 + ch2]);
                bf[i] = ldsv8(&Bb[(wn + i * 16 + lr) * 32 + ch2]);
            }
#pragma unroll
            for (int i = 0; i < 4; i++)
#pragma unroll
                for (int j = 0; j < 4; j++)
                    acc[i][j] = __builtin_amdgcn_mfma_f32_16x16x32_bf16(af[i], bf[j], acc[i][j], 0, 0, 0);
        };

        const int NIT = KL >> 5;
        issue32(0, 0);
        for (int it = 0; it < NIT; ++it) {
            const int nxt = it + 1;
            if (nxt < NIT) {
                issue32(nxt & 1, nxt << 5);
                __builtin_amdgcn_sched_barrier(0);
                __builtin_amdgcn_s_waitcnt(0x0F74);   // vmcnt(4): iter-it loads done
            } else {
                __builtin_amdgcn_sched_barrier(0);
                __builtin_amdgcn_s_waitcnt(0x0F70);   // vmcnt(0)
            }
            __builtin_amdgcn_s_barrier();
            __builtin_amdgcn_sched_barrier(0);
            compute32(it & 1);
            __builtin_amdgcn_sched_barrier(0);
            __builtin_amdgcn_s_barrier();             // readers done before buf reuse
            __builtin_amdgcn_sched_barrier(0);
        }
    } else {
        // ---- BK=64 dbuf (legacy) ----
        const int sr = lane >> 3, sc = lane & 7;
        const int fch = sc ^ sr;
        const unsigned short* Ag = A + (size_t)(m0 + w * 32 + sr) * K + kbase + fch * 8;
        const unsigned short* Bg = Bt + (size_t)(n0 + w * 32 + sr) * K + kbase + fch * 8;
        const int ch0 = quad ^ (lr & 7);
        const int ch1 = (4 + quad) ^ (lr & 7);

        auto issue = [&](int buf, int k0) {
            unsigned short* Al = &As[buf][(w * 32) * 64];
            unsigned short* Bl = &Bs[buf][(w * 32) * 64];
#pragma unroll
            for (int i = 0; i < 4; i++) {
                async16(Ag + (size_t)(i * 8) * K + k0, Al + (i * 8) * 64);
                async16(Bg + (size_t)(i * 8) * K + k0, Bl + (i * 8) * 64);
            }
        };
        auto compute = [&](int buf) {
            const unsigned short* Ab = As[buf];
            const unsigned short* Bb = Bs[buf];
#pragma unroll
            for (int kk = 0; kk < 2; kk++) {
                const int ch = kk ? ch1 : ch0;
                bf16x8 af[4], bf[4];
#pragma unroll
                for (int i = 0; i < 4; i++) {
                    af[i] = ldsv8(&Ab[(wm + i * 16 + lr) * 64 + ch * 8]);
                    bf[i] = ldsv8(&Bb[(wn + i * 16 + lr) * 64 + ch * 8]);
                }
#pragma unroll
                for (int i = 0; i < 4; i++)
#pragma unroll
                    for (int j = 0; j < 4; j++)
                        acc[i][j] = __builtin_amdgcn_mfma_f32_16x16x32_bf16(af[i], bf[j], acc[i][j], 0, 0, 0);
            }
        };

        const int NIT = KL >> 6;
        issue(0, 0);
        for (int it = 0; it < NIT; ++it) {
            const int nxt = it + 1;
            if (nxt < NIT) {
                issue(nxt & 1, nxt << 6);
                __builtin_amdgcn_sched_barrier(0);
                __builtin_amdgcn_s_waitcnt(0x0F78);   // vmcnt(8): iter-it loads done
            } else {
                __builtin_amdgcn_sched_barrier(0);
                __builtin_amdgcn_s_waitcnt(0x0F70);   // vmcnt(0)
            }
            __builtin_amdgcn_s_barrier();
            __builtin_amdgcn_sched_barrier(0);
            compute(it & 1);
            __builtin_amdgcn_sched_barrier(0);
            __builtin_amdgcn_s_barrier();             // readers done before buf reuse
            __builtin_amdgcn_sched_barrier(0);
        }
    }

    if (vrel >= 0) {
        // ---- V^T pos-permuted epilogue ----
        const int crel = vrel + wn;                   // multiple of 64
        const int hh = crel >> 6;
        const int bidx = (m0 + wm) >> 10;
        const int tbase = ((m0 + wm) & 1023) + quad * 16;
#pragma unroll
        for (int j = 0; j < 4; j++) {
            const float bv = bias ? bias[n0 + wn + j * 16 + lr] : 0.f;
            const int d = j * 16 + lr;
            unsigned short* vp = VTout + ((size_t)(bidx * 16 + hh) * 64 + d) * 1024 + tbase;
#pragma unroll
            for (int r = 0; r < 4; r++) {
                uint2v u = { f2bf2(acc[0][j][r] + bv, acc[1][j][r] + bv),
                             f2bf2(acc[2][j][r] + bv, acc[3][j][r] + bv) };
                *(uint2v*)(vp + r * 4) = u;
            }
        }
        return;
    }

#pragma unroll
    for (int j = 0; j < 4; j++) {
        const int col = n0 + wn + j * 16 + lr;
        const float bv = bias ? bias[col] : 0.f;
#pragma unroll
        for (int i = 0; i < 4; i++) {
            const int row0 = m0 + wm + i * 16 + quad * 4;
#pragma unroll
            for (int r = 0; r < 4; r++) {
                float v = (acc[i][j][r] + bv) * qs;
                if (RELU) v = fmaxf(v, 0.f);
                Cout[outoff + (size_t)(row0 + r) * ldc + col] = f2bf1(v);
            }
        }
    }
}

// Generic GEMM kernel (runtime order, split-K via gridDim.z, qscale cols, V cols)
template <int RELU, int MODE>
__global__ __launch_bounds__(256) void gemm_bt(
    const unsigned short* __restrict__ A, const unsigned short* __restrict__ Bt,
    const float* __restrict__ bias, unsigned short* __restrict__ Cout,
    int M, int N, int K, int ldc, int order, int qcols, int vcol0,
    unsigned short* __restrict__ VTout)
{
    const int m0 = (order ? blockIdx.x : blockIdx.y) * 128;
    const int n0 = (order ? blockIdx.y : blockIdx.x) * 128;
    const int KL = K / gridDim.z;
    const int kbase = blockIdx.z * KL;
    const float qs = (n0 < qcols) ? 0.015625f : 1.0f;
    const int vrel = (n0 >= vcol0) ? n0 - vcol0 : -1;
    const size_t outoff = (size_t)blockIdx.z * M * ldc;
    gemm_core<RELU, MODE>(A, Bt, bias, Cout, m0, n0, K, KL, kbase, ldc,
                          qs, vrel, VTout, outoff);
}

// Fused cross-phase GEMM: y<8 -> CQ = SANb@WtCWQ^T (1/64-scaled);
// y in [8,16) -> CK = cxb@WtCKV^T cols [0,1024); y in [16,24) -> V^T epilogue.
__global__ __launch_bounds__(256) void gemm_cross(
    const unsigned short* __restrict__ SANb, const unsigned short* __restrict__ WtCWQ,
    const float* __restrict__ cbq, unsigned short* __restrict__ CQ,
    const unsigned short* __restrict__ cxb, const unsigned short* __restrict__ WtCKV,
    const float* __restrict__ biasC, unsigned short* __restrict__ CKb,
    unsigned short* __restrict__ VTc)
{
    const int m0 = blockIdx.x * 128;
    const int y = blockIdx.y;
    const unsigned short *Ax, *Btx;
    const float* bx;
    unsigned short* Cx = nullptr;
    unsigned short* vt = nullptr;
    int n0, ldc = 1024, vrel = -1;
    float qs = 1.0f;
    if (y < 8) {
        Ax = SANb; Btx = WtCWQ; bx = cbq; Cx = CQ; n0 = y * 128; qs = 0.015625f;
    } else {
        Ax = cxb; Btx = WtCKV; bx = biasC; n0 = (y - 8) * 128;
        if (n0 < 1024) Cx = CKb;
        else { vrel = n0 - 1024; vt = VTc; }
    }
    gemm_core<0, 0>(Ax, Btx, bx, Cx, m0, n0, 1024, 1024, 0, ldc, qs, vrel, vt, 0);
}

// ---------------- MFMA flash attention (bf16 in/out), no-max variant -----------
// One block per (b, h, 64 q-rows) -> grid 1024, 4 waves x 16 q-rows, 44 KB LDS,
// 3 blocks/CU. Double-buffered K/V (counted vmcnt(4)), mask in LDS, setprio on
// MFMA clusters. XCD-chunked: chunk of 128 blocks = 8 heads of one batch.
__global__ __launch_bounds__(256) void attn_mfma(
    const unsigned short* __restrict__ Q, int qs,
    const unsigned short* __restrict__ K, int kvs,
    const unsigned short* __restrict__ VT,     // [(b*16+h)*64+d][1024], pos-permuted
    const float* __restrict__ maskf,           // [b][1024]
    unsigned short* __restrict__ O)
{
    __shared__ __align__(16) unsigned short Ks[2][64 * 64];   // [key][d]
    __shared__ __align__(16) unsigned short Vt[2][64 * 64];   // [d][pos]
    __shared__ __align__(16) unsigned short Pb[64 * 64];      // [q][pos]
    __shared__ float msk[1024];

    const int bid = blockIdx.x;
    const int jdx = (bid & 7) * 128 + (bid >> 3);
    const int q0 = (jdx & 15) * 64, h = (jdx >> 4) & 15, b = jdx >> 8;
    const int tid = threadIdx.x;
    const int w = tid >> 6, lane = tid & 63;
    const int lr = lane & 15, quad = lane >> 4;
    const int wm = w * 16;
    const float4v zf = {0.f, 0.f, 0.f, 0.f};

    // stage mask row into LDS (removes per-iter global loads from vmcnt ledger)
    ((float4v*)msk)[tid] = ((const float4v*)(maskf + b * 1024))[tid];

    bf16x8 qf[2];
#pragma unroll
    for (int c = 0; c < 2; c++)
        qf[c] = ldsv8(Q + (size_t)(b * 1024 + q0 + wm + lr) * qs
                      + h * 64 + c * 32 + quad * 8);

    const int sr = lane >> 3, sc = lane & 7;
    const int fch = sc ^ sr;
    const int ch0 = quad ^ (lr & 7), ch1 = (4 + quad) ^ (lr & 7);
    const unsigned short* VTb = VT + (size_t)(b * 16 + h) * 64 * 1024;

    __syncthreads();   // msk visible to all waves

    float4v oac[4];
    float lsum[4];
#pragma unroll
    for (int jj = 0; jj < 4; jj++) { oac[jj] = zf; lsum[jj] = 0.f; }

    auto issue = [&](int kb, int buf) {
        const int s0 = kb * 64;
#pragma unroll
        for (int i = 0; i < 2; i++) {
            async16(K + (size_t)(b * 1024 + s0 + w * 16 + i * 8 + sr) * kvs + h * 64 + fch * 8,
                    &Ks[buf][(w * 16 + i * 8) * 64]);
            async16(VTb + (size_t)(w * 16 + i * 8 + sr) * 1024 + s0 + fch * 8,
                    &Vt[buf][(w * 16 + i * 8) * 64]);
        }
    };

    issue(0, 0);   // 4 loads/wave in flight
    for (int kb = 0; kb < 16; ++kb) {
        const int cur = kb & 1;
        const int nxt = kb + 1;
        if (nxt < 16) {
            issue(nxt, nxt & 1);                     // buf cur^1: readers done at prev-iter barrier
            __builtin_amdgcn_sched_barrier(0);
            __builtin_amdgcn_s_waitcnt(0x0F74);      // vmcnt(4): tile-kb loads landed
        } else {
            __builtin_amdgcn_sched_barrier(0);
            __builtin_amdgcn_s_waitcnt(0x0F70);      // vmcnt(0)
        }
        __builtin_amdgcn_s_barrier();                // all waves' tile-kb data in LDS
        __builtin_amdgcn_sched_barrier(0);

        float mf[4];
#pragma unroll
        for (int jj = 0; jj < 4; jj++)
            mf[jj] = msk[kb * 64 + jj * 16 + lr];

        // ---- QK^T: 16 q-rows x 64 keys per wave ----
        float4v sa[4];
        __builtin_amdgcn_s_setprio(1);
#pragma unroll
        for (int jj = 0; jj < 4; jj++) {
            const int krow = jj * 16 + lr;
            bf16x8 kf0 = ldsv8(&Ks[cur][krow * 64 + ch0 * 8]);
            bf16x8 kf1 = ldsv8(&Ks[cur][krow * 64 + ch1 * 8]);
            sa[jj] = __builtin_amdgcn_mfma_f32_16x16x32_bf16(qf[0], kf0, zf, 0, 0, 0);
            sa[jj] = __builtin_amdgcn_mfma_f32_16x16x32_bf16(qf[1], kf1, sa[jj], 0, 0, 0);
        }
        __builtin_amdgcn_s_setprio(0);

        // ---- p = exp(s) * mask; lane-local l partials; packed b64 P stores ----
#pragma unroll
        for (int rr = 0; rr < 4; rr++) {
            const float p0 = __expf(sa[0][rr]) * mf[0];
            const float p1 = __expf(sa[1][rr]) * mf[1];
            const float p2 = __expf(sa[2][rr]) * mf[2];
            const float p3 = __expf(sa[3][rr]) * mf[3];
            lsum[rr] += (p0 + p1) + (p2 + p3);
            const int row = wm + quad * 4 + rr;
            const int schp = (lr >> 1) ^ (row & 7);
            uint2v pk = { f2bf2(p0, p1), f2bf2(p2, p3) };
            *(uint2v*)&Pb[row * 64 + schp * 8 + (lr & 1) * 4] = pk;
        }
        // Pb rows of this wave written & read by the same wave -> no barrier

        // ---- PV: O += P @ V (both in permuted-key pos order) ----
        bf16x8 pf[2];
#pragma unroll
        for (int c = 0; c < 2; c++)
            pf[c] = ldsv8(&Pb[(wm + lr) * 64 + (c ? ch1 : ch0) * 8]);
        __builtin_amdgcn_s_setprio(1);
#pragma unroll
        for (int jj = 0; jj < 4; jj++) {
            bf16x8 vf0 = ldsv8(&Vt[cur][(jj * 16 + lr) * 64 + ch0 * 8]);
            bf16x8 vf1 = ldsv8(&Vt[cur][(jj * 16 + lr) * 64 + ch1 * 8]);
            oac[jj] = __builtin_amdgcn_mfma_f32_16x16x32_bf16(pf[0], vf0, oac[jj], 0, 0, 0);
            oac[jj] = __builtin_amdgcn_mfma_f32_16x16x32_bf16(pf[1], vf1, oac[jj], 0, 0, 0);
        }
        __builtin_amdgcn_s_setprio(0);

        __builtin_amdgcn_sched_barrier(0);
        __builtin_amdgcn_s_barrier();                // readers done before buf reuse
        __builtin_amdgcn_sched_barrier(0);
    }

    // ---- epilogue: reduce l across the row's 16 lanes, divide, store ----
#pragma unroll
    for (int rr = 0; rr < 4; rr++) {
        float l = lsum[rr];
        l += __shfl_xor(l, 1);
        l += __shfl_xor(l, 2);
        l += __shfl_xor(l, 4);
        l += __shfl_xor(l, 8);
        const float inv = 1.0f / l;
        const int row = q0 + wm + quad * 4 + rr;
        unsigned short* op = O + (size_t)(b * 1024 + row) * 1024 + h * 64;
#pragma unroll
        for (int jj = 0; jj < 4; jj++)
            op[jj * 16 + lr] = f2bf1(oac[jj][rr] * inv);
    }
}

// ------------- fused partial-sum(bf16) + bias + residual-add + LayerNorm --------
#define PSTRIDE ((size_t)4096 * 1024)
__global__ __launch_bounds__(256) void add_ln_kernel(
    const unsigned short* __restrict__ P, int nparts, const float* __restrict__ lbias,
    const float* __restrict__ R,
    const float* __restrict__ g, const float* __restrict__ bb,
    float* __restrict__ outF, unsigned short* __restrict__ outB)
{
    const int row = blockIdx.x, tid = threadIdx.x;
    float4v z = ((const float4v*)(R + (size_t)row * 1024))[tid];
    for (int p = 0; p < nparts; ++p)
        z += bf4_to_f4(*(const uint2v*)(P + p * PSTRIDE + (size_t)row * 1024 + tid * 4));
    if (lbias) z += ((const float4v*)lbias)[tid];
    float s = z.x + z.y + z.z + z.w;
    float sq = z.x * z.x + z.y * z.y + z.z * z.z + z.w * z.w;
#pragma unroll
    for (int off = 32; off > 0; off >>= 1) {
        s += __shfl_down(s, off);
        sq += __shfl_down(sq, off);
    }
    __shared__ float ws[4], wsq[4];
    __shared__ float sm, sr;
    if ((tid & 63) == 0) { ws[tid >> 6] = s; wsq[tid >> 6] = sq; }
    __syncthreads();
    if (tid == 0) {
        float S1 = ws[0] + ws[1] + ws[2] + ws[3];
        float S2 = wsq[0] + wsq[1] + wsq[2] + wsq[3];
        float mean = S1 * (1.0f / 1024.0f);
        float var = S2 * (1.0f / 1024.0f) - mean * mean;
        sm = mean;
        sr = rsqrtf(var + 1e-5f);
    }
    __syncthreads();
    const float mean = sm, rstd = sr;
    const float4v* g4 = (const float4v*)g;
    const float4v* b4 = (const float4v*)bb;
    float4v res = g4[tid] * ((z - mean) * rstd) + b4[tid];
    if (outF) ((float4v*)(outF + (size_t)row * 1024))[tid] = res;
    if (outB) {
        uint2v u = { f2bf2(res.x, res.y), f2bf2(res.z, res.w) };
        *(uint2v*)(outB + (size_t)row * 1024 + tid * 4) = u;
    }
}

// ---------------- transpose + convert body: S[R][C] f32 -> D[C][R] bf16 ---------
__device__ __forceinline__ void tconv_body(const float* __restrict__ S,
                                           unsigned short* __restrict__ D,
                                           int R, int C, int r0, int c0)
{
    __shared__ float tile[64][65];
    const int tid = threadIdx.x;
    const int tr = tid >> 4, tc4 = (tid & 15) * 4;
#pragma unroll
    for (int i = 0; i < 4; i++) {
        const int rr = i * 16 + tr;
        *(float4v*)&tile[rr][tc4] = *(const float4v*)(S + (size_t)(r0 + rr) * C + c0 + tc4);
    }
    __syncthreads();
#pragma unroll
    for (int i = 0; i < 4; i++) {
        const int dr = i * 16 + tr;   // dst row = src col
        float v0 = tile[tc4 + 0][dr];
        float v1 = tile[tc4 + 1][dr];
        float v2 = tile[tc4 + 2][dr];
        float v3 = tile[tc4 + 3][dr];
        uint2v u = { f2bf2(v0, v1), f2bf2(v2, v3) };
        *(uint2v*)(D + (size_t)(c0 + dr) * R + r0 + tc4) = u;
    }
}

// ---------------- single fused prep kernel --------------------------------------
// blocks [0,8192): x/cx f32->bf16; [8192,10240): 8 square 1024^2 transposes;
// [10240,11264): W1^T; [11264,12288): W2^T; [12288,12340): biases+masks.
__global__ __launch_bounds__(256) void prep_all(
    const float* __restrict__ x, const float* __restrict__ cx,
    unsigned short* __restrict__ xb, unsigned short* __restrict__ cxb,
    const float* s0, const float* s1, const float* s2, const float* s3,
    const float* s4, const float* s5, const float* s6, const float* s7,
    unsigned short* d0, unsigned short* d1, unsigned short* d2, unsigned short* d3,
    unsigned short* d4, unsigned short* d5, unsigned short* d6, unsigned short* d7,
    const float* __restrict__ W1, unsigned short* __restrict__ WtW1,
    const float* __restrict__ W2, unsigned short* __restrict__ WtW2,
    const float* __restrict__ sbq, const float* __restrict__ sbk, const float* __restrict__ sbv,
    const float* __restrict__ cbk, const float* __restrict__ cbv,
    const int* __restrict__ smask, const int* __restrict__ cmask,
    float* __restrict__ bq, float* __restrict__ bc,
    float* __restrict__ smf, float* __restrict__ cmf)
{
    const int bid = blockIdx.x, tid = threadIdx.x;
    if (bid < 8192) {
        const float* s = bid < 4096 ? x : cx;
        unsigned short* d = bid < 4096 ? xb : cxb;
        const size_t i = ((size_t)(bid & 4095) * 256 + tid) * 4;
        float4v v = *(const float4v*)(s + i);
        uint2v u = { f2bf2(v.x, v.y), f2bf2(v.z, v.w) };
        *(uint2v*)(d + i) = u;
    } else if (bid < 10240) {
        const int t = bid - 8192;
        const int which = t >> 8, sub = t & 255;
        const float* S;
        unsigned short* D;
        switch (which) {
            case 0: S = s0; D = d0; break;
            case 1: S = s1; D = d1; break;
            case 2: S = s2; D = d2; break;
            case 3: S = s3; D = d3; break;
            case 4: S = s4; D = d4; break;
            case 5: S = s5; D = d5; break;
            case 6: S = s6; D = d6; break;
            default: S = s7; D = d7; break;
        }
        tconv_body(S, D, 1024, 1024, (sub >> 4) * 64, (sub & 15) * 64);
    } else if (bid < 11264) {
        const int t = bid - 10240;           // W1: R=1024, C=4096
        tconv_body(W1, WtW1, 1024, 4096, (t >> 6) * 64, (t & 63) * 64);
    } else if (bid < 12288) {
        const int t = bid - 11264;           // W2: R=4096, C=1024
        tconv_body(W2, WtW2, 4096, 1024, (t & 63) * 64, (t >> 6) * 64);
    } else {
        const int i = (bid - 12288) * 256 + tid;
        if (i < 3072)
            bq[i] = i < 1024 ? sbq[i] : (i < 2048 ? sbk[i - 1024] : sbv[i - 2048]);
        else if (i < 5120) {
            const int j = i - 3072;
            bc[j] = j < 1024 ? cbk[j] : cbv[j - 1024];
        } else if (i < 9216)
            smf[i - 5120] = (float)smask[i - 5120];
        else
            cmf[i - 9216] = (float)cmask[i - 9216];
    }
}

// --------------------------------------------------------------------------------
extern "C" void kernel_launch(void* const* d_in, const int* in_sizes, int n_in,
                              void* d_out, int out_size, void* d_ws, size_t ws_size,
                              hipStream_t stream)
{
    const float* x     = (const float*)d_in[0];
    const int*   smask = (const int*)d_in[1];
    const float* cx    = (const float*)d_in[2];
    const int*   cmask = (const int*)d_in[3];
    const float* sWq = (const float*)d_in[5],  *sbq = (const float*)d_in[6];
    const float* sWk = (const float*)d_in[7],  *sbk = (const float*)d_in[8];
    const float* sWv = (const float*)d_in[9],  *sbv = (const float*)d_in[10];
    const float* sWo = (const float*)d_in[11], *sbo = (const float*)d_in[12];
    const float* cWq = (const float*)d_in[13], *cbq = (const float*)d_in[14];
    const float* cWk = (const float*)d_in[15], *cbk = (const float*)d_in[16];
    const float* cWv = (const float*)d_in[17], *cbv = (const float*)d_in[18];
    const float* cWo = (const float*)d_in[19], *cbo = (const float*)d_in[20];
    const float* g   = (const float*)d_in[21], *bb  = (const float*)d_in[22];
    const float* W1  = (const float*)d_in[23], *b1  = (const float*)d_in[24];
    const float* W2  = (const float*)d_in[25], *b2  = (const float*)d_in[26];
    float* out = (float*)d_out;

    const size_t MB = 1024 * 1024;
    unsigned char* ws = (unsigned char*)d_ws;
    unsigned short* xb   = (unsigned short*)(ws + 0 * MB);    // 8 MB
    unsigned short* cxb  = (unsigned short*)(ws + 8 * MB);    // 8 MB
    unsigned short* SANb = (unsigned short*)(ws + 16 * MB);   // 8 MB
    unsigned short* CQ   = (unsigned short*)(ws + 24 * MB);   // 8 MB
    unsigned short* MID  = (unsigned short*)(ws + 0 * MB);    // 32 MB (FFN; xb..CQ dead)
    unsigned short* QK   = (unsigned short*)(ws + 32 * MB);   // 16 MB [4096][2048]
    unsigned short* VTs  = (unsigned short*)(ws + 48 * MB);   // 8 MB [(b,h,d)][1024]
    unsigned short* P    = (unsigned short*)(ws + 32 * MB);   // 4x8 MB bf16 partials
    unsigned short* CKb  = (unsigned short*)(ws + 56 * MB);   // 8 MB [4096][1024]
    unsigned short* VTc  = (unsigned short*)(ws + 64 * MB);   // 8 MB
    unsigned short* T    = (unsigned short*)(ws + 72 * MB);   // 8 MB
    float*          HH   = (float*)(ws + 80 * MB);            // 16 MB
    unsigned short* HHb  = (unsigned short*)(ws + 96 * MB);   // 8 MB
    unsigned short* WtQKV = (unsigned short*)(ws + 104 * MB); // 6 MB [3072][1024]
    unsigned short* WtCKV = (unsigned short*)(ws + 110 * MB); // 4 MB [2048][1024]
    unsigned short* WtSWO = (unsigned short*)(ws + 114 * MB); // 2 MB
    unsigned short* WtCWQ = (unsigned short*)(ws + 116 * MB); // 2 MB
    unsigned short* WtCWO = (unsigned short*)(ws + 118 * MB); // 2 MB
    unsigned short* WtW1  = (unsigned short*)(ws + 120 * MB); // 8 MB
    unsigned short* WtW2  = (unsigned short*)(ws + 128 * MB); // 8 MB
    float* biasQ = (float*)(ws + 136 * MB);                   // 12 KB
    float* biasC = (float*)(ws + 136 * MB + 16 * 1024);       // 8 KB
    float* smf   = (float*)(ws + 136 * MB + 32 * 1024);       // 16 KB
    float* cmf   = (float*)(ws + 136 * MB + 48 * 1024);       // 16 KB

    dim3 blk(256);

    // ---- all prep in one launch ----
    prep_all<<<12340, blk, 0, stream>>>(
        x, cx, xb, cxb,
        sWq, sWk, sWv, cWk, cWv, sWo, cWq, cWo,
        WtQKV, WtQKV + 1024 * 1024, WtQKV + 2 * 1024 * 1024,
        WtCKV, WtCKV + 1024 * 1024,
        WtSWO, WtCWQ, WtCWO,
        W1, WtW1, W2, WtW2,
        sbq, sbk, sbv, cbk, cbv, smask, cmask, biasQ, biasC, smf, cmf);

    // ---- self attention ----
    gemm_bt<0, 0><<<dim3(32, 24), blk, 0, stream>>>(
        xb, WtQKV, biasQ, QK, 4096, 3072, 1024, 2048, 1, 1024, 2048, VTs);
    attn_mfma<<<1024, blk, 0, stream>>>(QK, 2048, QK + 1024, 2048, VTs, smf, T);
    gemm_bt<0, 0><<<dim3(32, 8, 4), blk, 0, stream>>>(
        T, WtSWO, nullptr, P, 4096, 1024, 1024, 1024, 1, 0, VBIG, nullptr);
    add_ln_kernel<<<4096, blk, 0, stream>>>(P, 4, sbo, x, g, bb, nullptr, SANb);

    // ---- cross attention (residual = ORIGINAL x); CQ+CKV fused ----
    gemm_cross<<<dim3(32, 24), blk, 0, stream>>>(
        SANb, WtCWQ, cbq, CQ, cxb, WtCKV, biasC, CKb, VTc);
    attn_mfma<<<1024, blk, 0, stream>>>(CQ, 1024, CKb, 1024, VTc, cmf, T);
    gemm_bt<0, 0><<<dim3(32, 8, 4), blk, 0, stream>>>(
        T, WtCWO, nullptr, P, 4096, 1024, 1024, 1024, 1, 0, VBIG, nullptr);
    add_ln_kernel<<<4096, blk, 0, stream>>>(P, 4, cbo, x, g, bb, HH, HHb);

    // ---- FFN ----
    gemm_bt<1, 0><<<dim3(32, 32), blk, 0, stream>>>(
        HHb, WtW1, b1, MID, 4096, 4096, 1024, 4096, 0, 0, VBIG, nullptr);
    gemm_bt<0, 0><<<dim3(32, 8, 4), blk, 0, stream>>>(
        MID, WtW2, nullptr, P, 4096, 1024, 4096, 1024, 1, 0, VBIG, nullptr);
    add_ln_kernel<<<4096, blk, 0, stream>>>(P, 4, b2, HH, g, bb, out, nullptr);
}

// Round 8
// 475.014 us; speedup vs baseline: 1.1222x; 1.1222x over previous
//
#include <hip/hip_runtime.h>
#include <hip/hip_bf16.h>

// Decoder block: self-MHA -> add+LN -> cross-MHA -> add+LN(resid=orig x) -> FFN -> add+LN
// B=4 S=1024 H=1024 NH=16 d=64.
// R15 = exact reversion to the best-measured configuration (R7, 473.0 us).
// Session record (R8-R14): 8-phase 256^2 (-10%), +swizzle (-5%), GEMM XCD
// swizzle (FETCH +70%, time neutral -> fetch-insensitive), attn setprio/dbuf/
// re-tile (all neutral), BK=32 counted dbuf (-10%, line-split FETCH +20%).
// Conclusion: 128^2/BK=64 with DBUF as below is the measured optimum of the
// {occupancy x pipeline x locality} matrix for these shapes on this harness.

typedef float float4v __attribute__((ext_vector_type(4)));
typedef __bf16 bf16x8 __attribute__((ext_vector_type(8)));
typedef unsigned short ushort8 __attribute__((ext_vector_type(8)));
typedef unsigned int uint2v __attribute__((ext_vector_type(2)));

#define VBIG (1 << 29)

__device__ __forceinline__ unsigned short f2bf1(float f) {
    unsigned u = __builtin_bit_cast(unsigned, f);
    u += 0x7fffu + ((u >> 16) & 1u);
    return (unsigned short)(u >> 16);
}
__device__ __forceinline__ unsigned f2bf2(float lo, float hi) {
    unsigned a = __builtin_bit_cast(unsigned, lo);
    a += 0x7fffu + ((a >> 16) & 1u);
    unsigned b = __builtin_bit_cast(unsigned, hi);
    b += 0x7fffu + ((b >> 16) & 1u);
    return (a >> 16) | (b & 0xffff0000u);
}
__device__ __forceinline__ float4v bf4_to_f4(uint2v u) {
    float4v r;
    r.x = __builtin_bit_cast(float, (u.x & 0xffffu) << 16);
    r.y = __builtin_bit_cast(float, u.x & 0xffff0000u);
    r.z = __builtin_bit_cast(float, (u.y & 0xffffu) << 16);
    r.w = __builtin_bit_cast(float, u.y & 0xffff0000u);
    return r;
}
__device__ __forceinline__ bf16x8 ldsv8(const unsigned short* p) {
    return __builtin_bit_cast(bf16x8, *(const ushort8*)p);
}
// async global->LDS, 16B per lane; LDS dest = wave-uniform base + lane*16
__device__ __forceinline__ void async16(const unsigned short* g, unsigned short* l) {
    __builtin_amdgcn_global_load_lds(
        (const __attribute__((address_space(1))) unsigned int*)(g),
        (__attribute__((address_space(3))) unsigned int*)(l),
        16, 0, 0);
}

// ---------------- GEMM core: C[M,N] = A[M,K] @ Bt[N,K]^T (+ bias) --------------
// 128x128 tile, BK=64, 4 waves 2x2 of 64x64, 16x16x32 MFMA. bf16 output always.
// vrel >= 0: V^T pos-permuted epilogue into VTout (token t -> (t&~63)+pos(t&63),
// pos(k)=(k&15)*4+(k>>4)); vrel = col offset rel. to V region start.
template <int RELU, int DBUF>
__device__ __forceinline__ void gemm_core(
    const unsigned short* __restrict__ A, const unsigned short* __restrict__ Bt,
    const float* __restrict__ bias, unsigned short* __restrict__ Cout,
    int m0, int n0, int K, int KL, int kbase, int ldc,
    float qs, int vrel, unsigned short* __restrict__ VTout, size_t outoff)
{
    __shared__ __align__(16) unsigned short As[(DBUF ? 2 : 1) * 128 * 64];
    __shared__ __align__(16) unsigned short Bs[(DBUF ? 2 : 1) * 128 * 64];

    const int tid = threadIdx.x;
    const int w = tid >> 6, lane = tid & 63;
    const int lr = lane & 15, quad = lane >> 4;
    const int wm = (w >> 1) * 64, wn = (w & 1) * 64;

    const int sr = lane >> 3, sc = lane & 7;
    const int fch = sc ^ sr;                       // swizzled source chunk
    const unsigned short* Ag = A + (size_t)(m0 + w * 32 + sr) * K + kbase + fch * 8;
    const unsigned short* Bg = Bt + (size_t)(n0 + w * 32 + sr) * K + kbase + fch * 8;

    float4v acc[4][4];
#pragma unroll
    for (int i = 0; i < 4; i++)
#pragma unroll
        for (int j = 0; j < 4; j++) acc[i][j] = 0.f;

    const int ch0 = quad ^ (lr & 7);
    const int ch1 = (4 + quad) ^ (lr & 7);

    auto issue = [&](int buf, int k0) {
        unsigned short* Al = &As[buf * (128 * 64) + (w * 32) * 64];
        unsigned short* Bl = &Bs[buf * (128 * 64) + (w * 32) * 64];
#pragma unroll
        for (int i = 0; i < 4; i++) {
            async16(Ag + (size_t)(i * 8) * K + k0, Al + (i * 8) * 64);
            async16(Bg + (size_t)(i * 8) * K + k0, Bl + (i * 8) * 64);
        }
    };
    auto compute = [&](int buf) {
        const unsigned short* Ab = &As[buf * (128 * 64)];
        const unsigned short* Bb = &Bs[buf * (128 * 64)];
#pragma unroll
        for (int kk = 0; kk < 2; kk++) {
            const int ch = kk ? ch1 : ch0;
            bf16x8 af[4], bf[4];
#pragma unroll
            for (int i = 0; i < 4; i++) {
                af[i] = ldsv8(&Ab[(wm + i * 16 + lr) * 64 + ch * 8]);
                bf[i] = ldsv8(&Bb[(wn + i * 16 + lr) * 64 + ch * 8]);
            }
#pragma unroll
            for (int i = 0; i < 4; i++)
#pragma unroll
                for (int j = 0; j < 4; j++)
                    acc[i][j] = __builtin_amdgcn_mfma_f32_16x16x32_bf16(af[i], bf[j], acc[i][j], 0, 0, 0);
        }
    };

    if (DBUF) {
        const int NIT = KL >> 6;
        issue(0, 0);
        for (int it = 0; it < NIT; ++it) {
            const int nxt = it + 1;
            if (nxt < NIT) {
                issue(nxt & 1, nxt << 6);
                __builtin_amdgcn_sched_barrier(0);
                __builtin_amdgcn_s_waitcnt(0x0F78);   // vmcnt(8): iter-it loads done
            } else {
                __builtin_amdgcn_sched_barrier(0);
                __builtin_amdgcn_s_waitcnt(0x0F70);   // vmcnt(0)
            }
            __builtin_amdgcn_s_barrier();
            __builtin_amdgcn_sched_barrier(0);
            compute(it & 1);
            __builtin_amdgcn_sched_barrier(0);
            __builtin_amdgcn_s_barrier();             // readers done before buf reuse
            __builtin_amdgcn_sched_barrier(0);
        }
    } else {
        for (int k0 = 0; k0 < KL; k0 += 64) {
            issue(0, k0);
            __syncthreads();
            compute(0);
            __syncthreads();
        }
    }

    if (vrel >= 0) {
        // ---- V^T pos-permuted epilogue ----
        const int crel = vrel + wn;                   // multiple of 64
        const int hh = crel >> 6;
        const int bidx = (m0 + wm) >> 10;
        const int tbase = ((m0 + wm) & 1023) + quad * 16;
#pragma unroll
        for (int j = 0; j < 4; j++) {
            const float bv = bias ? bias[n0 + wn + j * 16 + lr] : 0.f;
            const int d = j * 16 + lr;
            unsigned short* vp = VTout + ((size_t)(bidx * 16 + hh) * 64 + d) * 1024 + tbase;
#pragma unroll
            for (int r = 0; r < 4; r++) {
                uint2v u = { f2bf2(acc[0][j][r] + bv, acc[1][j][r] + bv),
                             f2bf2(acc[2][j][r] + bv, acc[3][j][r] + bv) };
                *(uint2v*)(vp + r * 4) = u;
            }
        }
        return;
    }

#pragma unroll
    for (int j = 0; j < 4; j++) {
        const int col = n0 + wn + j * 16 + lr;
        const float bv = bias ? bias[col] : 0.f;
#pragma unroll
        for (int i = 0; i < 4; i++) {
            const int row0 = m0 + wm + i * 16 + quad * 4;
#pragma unroll
            for (int r = 0; r < 4; r++) {
                float v = (acc[i][j][r] + bv) * qs;
                if (RELU) v = fmaxf(v, 0.f);
                Cout[outoff + (size_t)(row0 + r) * ldc + col] = f2bf1(v);
            }
        }
    }
}

// Generic GEMM kernel (runtime order, split-K via gridDim.z, qscale cols, V cols)
template <int RELU, int DBUF>
__global__ __launch_bounds__(256) void gemm_bt(
    const unsigned short* __restrict__ A, const unsigned short* __restrict__ Bt,
    const float* __restrict__ bias, unsigned short* __restrict__ Cout,
    int M, int N, int K, int ldc, int order, int qcols, int vcol0,
    unsigned short* __restrict__ VTout)
{
    const int m0 = (order ? blockIdx.x : blockIdx.y) * 128;
    const int n0 = (order ? blockIdx.y : blockIdx.x) * 128;
    const int KL = K / gridDim.z;
    const int kbase = blockIdx.z * KL;
    const float qs = (n0 < qcols) ? 0.015625f : 1.0f;
    const int vrel = (n0 >= vcol0) ? n0 - vcol0 : -1;
    const size_t outoff = (size_t)blockIdx.z * M * ldc;
    gemm_core<RELU, DBUF>(A, Bt, bias, Cout, m0, n0, K, KL, kbase, ldc,
                          qs, vrel, VTout, outoff);
}

// Fused cross-phase GEMM: y<8 -> CQ = SANb@WtCWQ^T (1/64-scaled);
// y in [8,16) -> CK = cxb@WtCKV^T cols [0,1024); y in [16,24) -> V^T epilogue.
__global__ __launch_bounds__(256) void gemm_cross(
    const unsigned short* __restrict__ SANb, const unsigned short* __restrict__ WtCWQ,
    const float* __restrict__ cbq, unsigned short* __restrict__ CQ,
    const unsigned short* __restrict__ cxb, const unsigned short* __restrict__ WtCKV,
    const float* __restrict__ biasC, unsigned short* __restrict__ CKb,
    unsigned short* __restrict__ VTc)
{
    const int m0 = blockIdx.x * 128;
    const int y = blockIdx.y;
    const unsigned short *Ax, *Btx;
    const float* bx;
    unsigned short* Cx = nullptr;
    unsigned short* vt = nullptr;
    int n0, ldc = 1024, vrel = -1;
    float qs = 1.0f;
    if (y < 8) {
        Ax = SANb; Btx = WtCWQ; bx = cbq; Cx = CQ; n0 = y * 128; qs = 0.015625f;
    } else {
        Ax = cxb; Btx = WtCKV; bx = biasC; n0 = (y - 8) * 128;
        if (n0 < 1024) Cx = CKb;
        else { vrel = n0 - 1024; vt = VTc; }
    }
    gemm_core<0, 0>(Ax, Btx, bx, Cx, m0, n0, 1024, 1024, 0, ldc, qs, vrel, vt, 0);
}

// ---------------- MFMA flash attention (bf16 in/out), no-max variant -----------
__global__ __launch_bounds__(256) void attn_mfma(
    const unsigned short* __restrict__ Q, int qs,
    const unsigned short* __restrict__ K, int kvs,
    const unsigned short* __restrict__ VT,     // [(b*16+h)*64+d][1024], pos-permuted
    const float* __restrict__ maskf,           // [b][1024]
    unsigned short* __restrict__ O)
{
    __shared__ __align__(16) unsigned short Ks[64 * 64];   // [key][d]
    __shared__ __align__(16) unsigned short Vt[64 * 64];   // [d][pos]
    __shared__ __align__(16) unsigned short Pb[128 * 64];  // [q][pos]

    const int tid = threadIdx.x;
    const int b = blockIdx.z, h = blockIdx.y, q0 = blockIdx.x * 128;
    const int w = tid >> 6, lane = tid & 63;
    const int lr = lane & 15, quad = lane >> 4;
    const int wm = w * 32;
    const float4v zf = {0.f, 0.f, 0.f, 0.f};

    bf16x8 qf[2][2];
#pragma unroll
    for (int i = 0; i < 2; i++)
#pragma unroll
        for (int c = 0; c < 2; c++)
            qf[i][c] = ldsv8(Q + (size_t)(b * 1024 + q0 + wm + i * 16 + lr) * qs
                             + h * 64 + c * 32 + quad * 8);

    const int sr = lane >> 3, sc = lane & 7;
    const int fch = sc ^ sr;
    const int ch0 = quad ^ (lr & 7), ch1 = (4 + quad) ^ (lr & 7);
    const unsigned short* VTb = VT + (size_t)(b * 16 + h) * 64 * 1024;

    float4v oac[2][4];
    float lsum[2][4];
#pragma unroll
    for (int i = 0; i < 2; i++) {
#pragma unroll
        for (int j = 0; j < 4; j++) oac[i][j] = zf;
#pragma unroll
        for (int rr = 0; rr < 4; rr++) lsum[i][rr] = 0.f;
    }

    for (int kb = 0; kb < 16; ++kb) {
        const int s0 = kb * 64;
        __syncthreads();   // prev iter's Ks/Vt reads done
#pragma unroll
        for (int i = 0; i < 2; i++) {
            async16(K + (size_t)(b * 1024 + s0 + w * 16 + i * 8 + sr) * kvs + h * 64 + fch * 8,
                    &Ks[(w * 16 + i * 8) * 64]);
            async16(VTb + (size_t)(w * 16 + i * 8 + sr) * 1024 + s0 + fch * 8,
                    &Vt[(w * 16 + i * 8) * 64]);
        }
        float mf[4];
#pragma unroll
        for (int j = 0; j < 4; j++)
            mf[j] = maskf[b * 1024 + s0 + j * 16 + lr];
        __syncthreads();

        // ---- QK^T: 32 q-rows x 64 keys per wave ----
        float4v sa[2][4];
#pragma unroll
        for (int j = 0; j < 4; j++) {
            const int krow = j * 16 + lr;
            bf16x8 kf0 = ldsv8(&Ks[krow * 64 + ch0 * 8]);
            bf16x8 kf1 = ldsv8(&Ks[krow * 64 + ch1 * 8]);
            sa[0][j] = __builtin_amdgcn_mfma_f32_16x16x32_bf16(qf[0][0], kf0, zf, 0, 0, 0);
            sa[0][j] = __builtin_amdgcn_mfma_f32_16x16x32_bf16(qf[0][1], kf1, sa[0][j], 0, 0, 0);
            sa[1][j] = __builtin_amdgcn_mfma_f32_16x16x32_bf16(qf[1][0], kf0, zf, 0, 0, 0);
            sa[1][j] = __builtin_amdgcn_mfma_f32_16x16x32_bf16(qf[1][1], kf1, sa[1][j], 0, 0, 0);
        }

        // ---- p = exp(s) * mask; lane-local l partials; packed b64 P stores ----
#pragma unroll
        for (int i = 0; i < 2; i++) {
#pragma unroll
            for (int rr = 0; rr < 4; rr++) {
                const float p0 = __expf(sa[i][0][rr]) * mf[0];
                const float p1 = __expf(sa[i][1][rr]) * mf[1];
                const float p2 = __expf(sa[i][2][rr]) * mf[2];
                const float p3 = __expf(sa[i][3][rr]) * mf[3];
                lsum[i][rr] += (p0 + p1) + (p2 + p3);
                const int row = wm + i * 16 + quad * 4 + rr;
                const int schp = (lr >> 1) ^ (row & 7);
                uint2v pk = { f2bf2(p0, p1), f2bf2(p2, p3) };
                *(uint2v*)&Pb[row * 64 + schp * 8 + (lr & 1) * 4] = pk;
            }
        }
        // Pb rows of this wave written & read by the same wave -> no barrier

        // ---- PV: O += P @ V (both in permuted-key pos order) ----
        bf16x8 pf[2][2];
#pragma unroll
        for (int i = 0; i < 2; i++)
#pragma unroll
            for (int c = 0; c < 2; c++)
                pf[i][c] = ldsv8(&Pb[(wm + i * 16 + lr) * 64 + (c ? ch1 : ch0) * 8]);
#pragma unroll
        for (int j = 0; j < 4; j++) {
            bf16x8 vf0 = ldsv8(&Vt[(j * 16 + lr) * 64 + ch0 * 8]);
            bf16x8 vf1 = ldsv8(&Vt[(j * 16 + lr) * 64 + ch1 * 8]);
            oac[0][j] = __builtin_amdgcn_mfma_f32_16x16x32_bf16(pf[0][0], vf0, oac[0][j], 0, 0, 0);
            oac[0][j] = __builtin_amdgcn_mfma_f32_16x16x32_bf16(pf[0][1], vf1, oac[0][j], 0, 0, 0);
            oac[1][j] = __builtin_amdgcn_mfma_f32_16x16x32_bf16(pf[1][0], vf0, oac[1][j], 0, 0, 0);
            oac[1][j] = __builtin_amdgcn_mfma_f32_16x16x32_bf16(pf[1][1], vf1, oac[1][j], 0, 0, 0);
        }
    }

    // ---- epilogue: reduce l across the row's 16 lanes, divide, store ----
#pragma unroll
    for (int i = 0; i < 2; i++)
#pragma unroll
        for (int rr = 0; rr < 4; rr++) {
            float l = lsum[i][rr];
            l += __shfl_xor(l, 1);
            l += __shfl_xor(l, 2);
            l += __shfl_xor(l, 4);
            l += __shfl_xor(l, 8);
            const float inv = 1.0f / l;
            const int row = q0 + wm + i * 16 + quad * 4 + rr;
            unsigned short* op = O + (size_t)(b * 1024 + row) * 1024 + h * 64;
#pragma unroll
            for (int j = 0; j < 4; j++)
                op[j * 16 + lr] = f2bf1(oac[i][j][rr] * inv);
        }
}

// ------------- fused partial-sum(bf16) + bias + residual-add + LayerNorm --------
#define PSTRIDE ((size_t)4096 * 1024)
__global__ __launch_bounds__(256) void add_ln_kernel(
    const unsigned short* __restrict__ P, int nparts, const float* __restrict__ lbias,
    const float* __restrict__ R,
    const float* __restrict__ g, const float* __restrict__ bb,
    float* __restrict__ outF, unsigned short* __restrict__ outB)
{
    const int row = blockIdx.x, tid = threadIdx.x;
    float4v z = ((const float4v*)(R + (size_t)row * 1024))[tid];
    for (int p = 0; p < nparts; ++p)
        z += bf4_to_f4(*(const uint2v*)(P + p * PSTRIDE + (size_t)row * 1024 + tid * 4));
    if (lbias) z += ((const float4v*)lbias)[tid];
    float s = z.x + z.y + z.z + z.w;
    float sq = z.x * z.x + z.y * z.y + z.z * z.z + z.w * z.w;
#pragma unroll
    for (int off = 32; off > 0; off >>= 1) {
        s += __shfl_down(s, off);
        sq += __shfl_down(sq, off);
    }
    __shared__ float ws[4], wsq[4];
    __shared__ float sm, sr;
    if ((tid & 63) == 0) { ws[tid >> 6] = s; wsq[tid >> 6] = sq; }
    __syncthreads();
    if (tid == 0) {
        float S1 = ws[0] + ws[1] + ws[2] + ws[3];
        float S2 = wsq[0] + wsq[1] + wsq[2] + wsq[3];
        float mean = S1 * (1.0f / 1024.0f);
        float var = S2 * (1.0f / 1024.0f) - mean * mean;
        sm = mean;
        sr = rsqrtf(var + 1e-5f);
    }
    __syncthreads();
    const float mean = sm, rstd = sr;
    const float4v* g4 = (const float4v*)g;
    const float4v* b4 = (const float4v*)bb;
    float4v res = g4[tid] * ((z - mean) * rstd) + b4[tid];
    if (outF) ((float4v*)(outF + (size_t)row * 1024))[tid] = res;
    if (outB) {
        uint2v u = { f2bf2(res.x, res.y), f2bf2(res.z, res.w) };
        *(uint2v*)(outB + (size_t)row * 1024 + tid * 4) = u;
    }
}

// ---------------- transpose + convert body: S[R][C] f32 -> D[C][R] bf16 ---------
__device__ __forceinline__ void tconv_body(const float* __restrict__ S,
                                           unsigned short* __restrict__ D,
                                           int R, int C, int r0, int c0)
{
    __shared__ float tile[64][65];
    const int tid = threadIdx.x;
    const int tr = tid >> 4, tc4 = (tid & 15) * 4;
#pragma unroll
    for (int i = 0; i < 4; i++) {
        const int rr = i * 16 + tr;
        *(float4v*)&tile[rr][tc4] = *(const float4v*)(S + (size_t)(r0 + rr) * C + c0 + tc4);
    }
    __syncthreads();
#pragma unroll
    for (int i = 0; i < 4; i++) {
        const int dr = i * 16 + tr;   // dst row = src col
        float v0 = tile[tc4 + 0][dr];
        float v1 = tile[tc4 + 1][dr];
        float v2 = tile[tc4 + 2][dr];
        float v3 = tile[tc4 + 3][dr];
        uint2v u = { f2bf2(v0, v1), f2bf2(v2, v3) };
        *(uint2v*)(D + (size_t)(c0 + dr) * R + r0 + tc4) = u;
    }
}

// ---------------- single fused prep kernel --------------------------------------
// blocks [0,8192): x/cx f32->bf16; [8192,10240): 8 square 1024^2 transposes;
// [10240,11264): W1^T; [11264,12288): W2^T; [12288,12340): biases+masks.
__global__ __launch_bounds__(256) void prep_all(
    const float* __restrict__ x, const float* __restrict__ cx,
    unsigned short* __restrict__ xb, unsigned short* __restrict__ cxb,
    const float* s0, const float* s1, const float* s2, const float* s3,
    const float* s4, const float* s5, const float* s6, const float* s7,
    unsigned short* d0, unsigned short* d1, unsigned short* d2, unsigned short* d3,
    unsigned short* d4, unsigned short* d5, unsigned short* d6, unsigned short* d7,
    const float* __restrict__ W1, unsigned short* __restrict__ WtW1,
    const float* __restrict__ W2, unsigned short* __restrict__ WtW2,
    const float* __restrict__ sbq, const float* __restrict__ sbk, const float* __restrict__ sbv,
    const float* __restrict__ cbk, const float* __restrict__ cbv,
    const int* __restrict__ smask, const int* __restrict__ cmask,
    float* __restrict__ bq, float* __restrict__ bc,
    float* __restrict__ smf, float* __restrict__ cmf)
{
    const int bid = blockIdx.x, tid = threadIdx.x;
    if (bid < 8192) {
        const float* s = bid < 4096 ? x : cx;
        unsigned short* d = bid < 4096 ? xb : cxb;
        const size_t i = ((size_t)(bid & 4095) * 256 + tid) * 4;
        float4v v = *(const float4v*)(s + i);
        uint2v u = { f2bf2(v.x, v.y), f2bf2(v.z, v.w) };
        *(uint2v*)(d + i) = u;
    } else if (bid < 10240) {
        const int t = bid - 8192;
        const int which = t >> 8, sub = t & 255;
        const float* S;
        unsigned short* D;
        switch (which) {
            case 0: S = s0; D = d0; break;
            case 1: S = s1; D = d1; break;
            case 2: S = s2; D = d2; break;
            case 3: S = s3; D = d3; break;
            case 4: S = s4; D = d4; break;
            case 5: S = s5; D = d5; break;
            case 6: S = s6; D = d6; break;
            default: S = s7; D = d7; break;
        }
        tconv_body(S, D, 1024, 1024, (sub >> 4) * 64, (sub & 15) * 64);
    } else if (bid < 11264) {
        const int t = bid - 10240;           // W1: R=1024, C=4096
        tconv_body(W1, WtW1, 1024, 4096, (t >> 6) * 64, (t & 63) * 64);
    } else if (bid < 12288) {
        const int t = bid - 11264;           // W2: R=4096, C=1024
        tconv_body(W2, WtW2, 4096, 1024, (t & 63) * 64, (t >> 6) * 64);
    } else {
        const int i = (bid - 12288) * 256 + tid;
        if (i < 3072)
            bq[i] = i < 1024 ? sbq[i] : (i < 2048 ? sbk[i - 1024] : sbv[i - 2048]);
        else if (i < 5120) {
            const int j = i - 3072;
            bc[j] = j < 1024 ? cbk[j] : cbv[j - 1024];
        } else if (i < 9216)
            smf[i - 5120] = (float)smask[i - 5120];
        else
            cmf[i - 9216] = (float)cmask[i - 9216];
    }
}

// --------------------------------------------------------------------------------
extern "C" void kernel_launch(void* const* d_in, const int* in_sizes, int n_in,
                              void* d_out, int out_size, void* d_ws, size_t ws_size,
                              hipStream_t stream)
{
    const float* x     = (const float*)d_in[0];
    const int*   smask = (const int*)d_in[1];
    const float* cx    = (const float*)d_in[2];
    const int*   cmask = (const int*)d_in[3];
    const float* sWq = (const float*)d_in[5],  *sbq = (const float*)d_in[6];
    const float* sWk = (const float*)d_in[7],  *sbk = (const float*)d_in[8];
    const float* sWv = (const float*)d_in[9],  *sbv = (const float*)d_in[10];
    const float* sWo = (const float*)d_in[11], *sbo = (const float*)d_in[12];
    const float* cWq = (const float*)d_in[13], *cbq = (const float*)d_in[14];
    const float* cWk = (const float*)d_in[15], *cbk = (const float*)d_in[16];
    const float* cWv = (const float*)d_in[17], *cbv = (const float*)d_in[18];
    const float* cWo = (const float*)d_in[19], *cbo = (const float*)d_in[20];
    const float* g   = (const float*)d_in[21], *bb  = (const float*)d_in[22];
    const float* W1  = (const float*)d_in[23], *b1  = (const float*)d_in[24];
    const float* W2  = (const float*)d_in[25], *b2  = (const float*)d_in[26];
    float* out = (float*)d_out;

    const size_t MB = 1024 * 1024;
    unsigned char* ws = (unsigned char*)d_ws;
    unsigned short* xb   = (unsigned short*)(ws + 0 * MB);    // 8 MB
    unsigned short* cxb  = (unsigned short*)(ws + 8 * MB);    // 8 MB
    unsigned short* SANb = (unsigned short*)(ws + 16 * MB);   // 8 MB
    unsigned short* CQ   = (unsigned short*)(ws + 24 * MB);   // 8 MB
    unsigned short* MID  = (unsigned short*)(ws + 0 * MB);    // 32 MB (FFN; xb..CQ dead)
    unsigned short* QK   = (unsigned short*)(ws + 32 * MB);   // 16 MB [4096][2048]
    unsigned short* VTs  = (unsigned short*)(ws + 48 * MB);   // 8 MB [(b,h,d)][1024]
    unsigned short* P    = (unsigned short*)(ws + 32 * MB);   // 2x8 MB bf16 partials
    unsigned short* CKb  = (unsigned short*)(ws + 56 * MB);   // 8 MB [4096][1024]
    unsigned short* VTc  = (unsigned short*)(ws + 64 * MB);   // 8 MB
    unsigned short* T    = (unsigned short*)(ws + 72 * MB);   // 8 MB
    float*          HH   = (float*)(ws + 80 * MB);            // 16 MB
    unsigned short* HHb  = (unsigned short*)(ws + 96 * MB);   // 8 MB
    unsigned short* WtQKV = (unsigned short*)(ws + 104 * MB); // 6 MB [3072][1024]
    unsigned short* WtCKV = (unsigned short*)(ws + 110 * MB); // 4 MB [2048][1024]
    unsigned short* WtSWO = (unsigned short*)(ws + 114 * MB); // 2 MB
    unsigned short* WtCWQ = (unsigned short*)(ws + 116 * MB); // 2 MB
    unsigned short* WtCWO = (unsigned short*)(ws + 118 * MB); // 2 MB
    unsigned short* WtW1  = (unsigned short*)(ws + 120 * MB); // 8 MB
    unsigned short* WtW2  = (unsigned short*)(ws + 128 * MB); // 8 MB
    float* biasQ = (float*)(ws + 136 * MB);                   // 12 KB
    float* biasC = (float*)(ws + 136 * MB + 16 * 1024);       // 8 KB
    float* smf   = (float*)(ws + 136 * MB + 32 * 1024);       // 16 KB
    float* cmf   = (float*)(ws + 136 * MB + 48 * 1024);       // 16 KB

    dim3 blk(256);

    // ---- all prep in one launch ----
    prep_all<<<12340, blk, 0, stream>>>(
        x, cx, xb, cxb,
        sWq, sWk, sWv, cWk, cWv, sWo, cWq, cWo,
        WtQKV, WtQKV + 1024 * 1024, WtQKV + 2 * 1024 * 1024,
        WtCKV, WtCKV + 1024 * 1024,
        WtSWO, WtCWQ, WtCWO,
        W1, WtW1, W2, WtW2,
        sbq, sbk, sbv, cbk, cbv, smask, cmask, biasQ, biasC, smf, cmf);

    // ---- self attention ----
    gemm_bt<0, 0><<<dim3(32, 24), blk, 0, stream>>>(
        xb, WtQKV, biasQ, QK, 4096, 3072, 1024, 2048, 1, 1024, 2048, VTs);
    attn_mfma<<<dim3(8, 16, 4), blk, 0, stream>>>(QK, 2048, QK + 1024, 2048, VTs, smf, T);
    gemm_bt<0, 1><<<dim3(32, 8, 2), blk, 0, stream>>>(
        T, WtSWO, nullptr, P, 4096, 1024, 1024, 1024, 1, 0, VBIG, nullptr);
    add_ln_kernel<<<4096, blk, 0, stream>>>(P, 2, sbo, x, g, bb, nullptr, SANb);

    // ---- cross attention (residual = ORIGINAL x); CQ+CKV fused ----
    gemm_cross<<<dim3(32, 24), blk, 0, stream>>>(
        SANb, WtCWQ, cbq, CQ, cxb, WtCKV, biasC, CKb, VTc);
    attn_mfma<<<dim3(8, 16, 4), blk, 0, stream>>>(CQ, 1024, CKb, 1024, VTc, cmf, T);
    gemm_bt<0, 1><<<dim3(32, 8, 2), blk, 0, stream>>>(
        T, WtCWO, nullptr, P, 4096, 1024, 1024, 1024, 1, 0, VBIG, nullptr);
    add_ln_kernel<<<4096, blk, 0, stream>>>(P, 2, cbo, x, g, bb, HH, HHb);

    // ---- FFN ----
    gemm_bt<1, 0><<<dim3(32, 32), blk, 0, stream>>>(
        HHb, WtW1, b1, MID, 4096, 4096, 1024, 4096, 0, 0, VBIG, nullptr);
    gemm_bt<0, 1><<<dim3(32, 8, 2), blk, 0, stream>>>(
        MID, WtW2, nullptr, P, 4096, 1024, 4096, 1024, 1, 0, VBIG, nullptr);
    add_ln_kernel<<<4096, blk, 0, stream>>>(P, 2, b2, HH, g, bb, out, nullptr);
}

// Round 9
// 473.732 us; speedup vs baseline: 1.1253x; 1.0027x over previous
//
#include <hip/hip_runtime.h>
#include <hip/hip_bf16.h>

// Decoder block: self-MHA -> add+LN -> cross-MHA -> add+LN(resid=orig x) -> FFN -> add+LN
// B=4 S=1024 H=1024 NH=16 d=64.
// R16 = R15 (best-measured 473-475us config) + critical-path restructure:
// cross-K/V projection (depends only on prep) merged into the self-QKV launch
// (grid 32x40); cross stage shrinks to CQ-only (32x8). GEMM core, attention,
// add_ln, prep all byte-identical to R15.

typedef float float4v __attribute__((ext_vector_type(4)));
typedef __bf16 bf16x8 __attribute__((ext_vector_type(8)));
typedef unsigned short ushort8 __attribute__((ext_vector_type(8)));
typedef unsigned int uint2v __attribute__((ext_vector_type(2)));

#define VBIG (1 << 29)

__device__ __forceinline__ unsigned short f2bf1(float f) {
    unsigned u = __builtin_bit_cast(unsigned, f);
    u += 0x7fffu + ((u >> 16) & 1u);
    return (unsigned short)(u >> 16);
}
__device__ __forceinline__ unsigned f2bf2(float lo, float hi) {
    unsigned a = __builtin_bit_cast(unsigned, lo);
    a += 0x7fffu + ((a >> 16) & 1u);
    unsigned b = __builtin_bit_cast(unsigned, hi);
    b += 0x7fffu + ((b >> 16) & 1u);
    return (a >> 16) | (b & 0xffff0000u);
}
__device__ __forceinline__ float4v bf4_to_f4(uint2v u) {
    float4v r;
    r.x = __builtin_bit_cast(float, (u.x & 0xffffu) << 16);
    r.y = __builtin_bit_cast(float, u.x & 0xffff0000u);
    r.z = __builtin_bit_cast(float, (u.y & 0xffffu) << 16);
    r.w = __builtin_bit_cast(float, u.y & 0xffff0000u);
    return r;
}
__device__ __forceinline__ bf16x8 ldsv8(const unsigned short* p) {
    return __builtin_bit_cast(bf16x8, *(const ushort8*)p);
}
// async global->LDS, 16B per lane; LDS dest = wave-uniform base + lane*16
__device__ __forceinline__ void async16(const unsigned short* g, unsigned short* l) {
    __builtin_amdgcn_global_load_lds(
        (const __attribute__((address_space(1))) unsigned int*)(g),
        (__attribute__((address_space(3))) unsigned int*)(l),
        16, 0, 0);
}

// ---------------- GEMM core: C[M,N] = A[M,K] @ Bt[N,K]^T (+ bias) --------------
// 128x128 tile, BK=64, 4 waves 2x2 of 64x64, 16x16x32 MFMA. bf16 output always.
// vrel >= 0: V^T pos-permuted epilogue into VTout (token t -> (t&~63)+pos(t&63),
// pos(k)=(k&15)*4+(k>>4)); vrel = col offset rel. to V region start.
template <int RELU, int DBUF>
__device__ __forceinline__ void gemm_core(
    const unsigned short* __restrict__ A, const unsigned short* __restrict__ Bt,
    const float* __restrict__ bias, unsigned short* __restrict__ Cout,
    int m0, int n0, int K, int KL, int kbase, int ldc,
    float qs, int vrel, unsigned short* __restrict__ VTout, size_t outoff)
{
    __shared__ __align__(16) unsigned short As[(DBUF ? 2 : 1) * 128 * 64];
    __shared__ __align__(16) unsigned short Bs[(DBUF ? 2 : 1) * 128 * 64];

    const int tid = threadIdx.x;
    const int w = tid >> 6, lane = tid & 63;
    const int lr = lane & 15, quad = lane >> 4;
    const int wm = (w >> 1) * 64, wn = (w & 1) * 64;

    const int sr = lane >> 3, sc = lane & 7;
    const int fch = sc ^ sr;                       // swizzled source chunk
    const unsigned short* Ag = A + (size_t)(m0 + w * 32 + sr) * K + kbase + fch * 8;
    const unsigned short* Bg = Bt + (size_t)(n0 + w * 32 + sr) * K + kbase + fch * 8;

    float4v acc[4][4];
#pragma unroll
    for (int i = 0; i < 4; i++)
#pragma unroll
        for (int j = 0; j < 4; j++) acc[i][j] = 0.f;

    const int ch0 = quad ^ (lr & 7);
    const int ch1 = (4 + quad) ^ (lr & 7);

    auto issue = [&](int buf, int k0) {
        unsigned short* Al = &As[buf * (128 * 64) + (w * 32) * 64];
        unsigned short* Bl = &Bs[buf * (128 * 64) + (w * 32) * 64];
#pragma unroll
        for (int i = 0; i < 4; i++) {
            async16(Ag + (size_t)(i * 8) * K + k0, Al + (i * 8) * 64);
            async16(Bg + (size_t)(i * 8) * K + k0, Bl + (i * 8) * 64);
        }
    };
    auto compute = [&](int buf) {
        const unsigned short* Ab = &As[buf * (128 * 64)];
        const unsigned short* Bb = &Bs[buf * (128 * 64)];
#pragma unroll
        for (int kk = 0; kk < 2; kk++) {
            const int ch = kk ? ch1 : ch0;
            bf16x8 af[4], bf[4];
#pragma unroll
            for (int i = 0; i < 4; i++) {
                af[i] = ldsv8(&Ab[(wm + i * 16 + lr) * 64 + ch * 8]);
                bf[i] = ldsv8(&Bb[(wn + i * 16 + lr) * 64 + ch * 8]);
            }
#pragma unroll
            for (int i = 0; i < 4; i++)
#pragma unroll
                for (int j = 0; j < 4; j++)
                    acc[i][j] = __builtin_amdgcn_mfma_f32_16x16x32_bf16(af[i], bf[j], acc[i][j], 0, 0, 0);
        }
    };

    if (DBUF) {
        const int NIT = KL >> 6;
        issue(0, 0);
        for (int it = 0; it < NIT; ++it) {
            const int nxt = it + 1;
            if (nxt < NIT) {
                issue(nxt & 1, nxt << 6);
                __builtin_amdgcn_sched_barrier(0);
                __builtin_amdgcn_s_waitcnt(0x0F78);   // vmcnt(8): iter-it loads done
            } else {
                __builtin_amdgcn_sched_barrier(0);
                __builtin_amdgcn_s_waitcnt(0x0F70);   // vmcnt(0)
            }
            __builtin_amdgcn_s_barrier();
            __builtin_amdgcn_sched_barrier(0);
            compute(it & 1);
            __builtin_amdgcn_sched_barrier(0);
            __builtin_amdgcn_s_barrier();             // readers done before buf reuse
            __builtin_amdgcn_sched_barrier(0);
        }
    } else {
        for (int k0 = 0; k0 < KL; k0 += 64) {
            issue(0, k0);
            __syncthreads();
            compute(0);
            __syncthreads();
        }
    }

    if (vrel >= 0) {
        // ---- V^T pos-permuted epilogue ----
        const int crel = vrel + wn;                   // multiple of 64
        const int hh = crel >> 6;
        const int bidx = (m0 + wm) >> 10;
        const int tbase = ((m0 + wm) & 1023) + quad * 16;
#pragma unroll
        for (int j = 0; j < 4; j++) {
            const float bv = bias ? bias[n0 + wn + j * 16 + lr] : 0.f;
            const int d = j * 16 + lr;
            unsigned short* vp = VTout + ((size_t)(bidx * 16 + hh) * 64 + d) * 1024 + tbase;
#pragma unroll
            for (int r = 0; r < 4; r++) {
                uint2v u = { f2bf2(acc[0][j][r] + bv, acc[1][j][r] + bv),
                             f2bf2(acc[2][j][r] + bv, acc[3][j][r] + bv) };
                *(uint2v*)(vp + r * 4) = u;
            }
        }
        return;
    }

#pragma unroll
    for (int j = 0; j < 4; j++) {
        const int col = n0 + wn + j * 16 + lr;
        const float bv = bias ? bias[col] : 0.f;
#pragma unroll
        for (int i = 0; i < 4; i++) {
            const int row0 = m0 + wm + i * 16 + quad * 4;
#pragma unroll
            for (int r = 0; r < 4; r++) {
                float v = (acc[i][j][r] + bv) * qs;
                if (RELU) v = fmaxf(v, 0.f);
                Cout[outoff + (size_t)(row0 + r) * ldc + col] = f2bf1(v);
            }
        }
    }
}

// Generic GEMM kernel (runtime order, split-K via gridDim.z, qscale cols, V cols)
template <int RELU, int DBUF>
__global__ __launch_bounds__(256) void gemm_bt(
    const unsigned short* __restrict__ A, const unsigned short* __restrict__ Bt,
    const float* __restrict__ bias, unsigned short* __restrict__ Cout,
    int M, int N, int K, int ldc, int order, int qcols, int vcol0,
    unsigned short* __restrict__ VTout)
{
    const int m0 = (order ? blockIdx.x : blockIdx.y) * 128;
    const int n0 = (order ? blockIdx.y : blockIdx.x) * 128;
    const int KL = K / gridDim.z;
    const int kbase = blockIdx.z * KL;
    const float qs = (n0 < qcols) ? 0.015625f : 1.0f;
    const int vrel = (n0 >= vcol0) ? n0 - vcol0 : -1;
    const size_t outoff = (size_t)blockIdx.z * M * ldc;
    gemm_core<RELU, DBUF>(A, Bt, bias, Cout, m0, n0, K, KL, kbase, ldc,
                          qs, vrel, VTout, outoff);
}

// Merged self-QKV + cross-K/V GEMM (both depend only on prep). grid (32, 40):
// y < 24: self QKV = xb@WtQKV^T -> QK[4096][2048] (cols<1024 q-scaled 1/64,
//         cols>=2048 -> V^T pos-permuted epilogue into VTs);
// y >= 24: cross K/V = cxb@WtCKV^T (n0<1024 -> CKb[4096][1024], else V^T
//         epilogue into VTc). Removes cross-K/V from the serial critical path.
__global__ __launch_bounds__(256) void gemm_qkv_ckv(
    const unsigned short* __restrict__ xb, const unsigned short* __restrict__ WtQKV,
    const float* __restrict__ biasQ, unsigned short* __restrict__ QK,
    unsigned short* __restrict__ VTs,
    const unsigned short* __restrict__ cxb, const unsigned short* __restrict__ WtCKV,
    const float* __restrict__ biasC, unsigned short* __restrict__ CKb,
    unsigned short* __restrict__ VTc)
{
    const int m0 = blockIdx.x * 128;
    const int y = blockIdx.y;
    const unsigned short *Ax, *Btx;
    const float* bx;
    unsigned short* Cx;
    unsigned short* vt;
    int n0, ldc, vrel = -1;
    float qs = 1.0f;
    if (y < 24) {
        Ax = xb; Btx = WtQKV; bx = biasQ; Cx = QK; vt = VTs; ldc = 2048;
        n0 = y * 128;
        if (n0 < 1024) qs = 0.015625f;
        if (n0 >= 2048) vrel = n0 - 2048;
    } else {
        Ax = cxb; Btx = WtCKV; bx = biasC; Cx = CKb; vt = VTc; ldc = 1024;
        n0 = (y - 24) * 128;
        if (n0 >= 1024) vrel = n0 - 1024;
    }
    gemm_core<0, 0>(Ax, Btx, bx, Cx, m0, n0, 1024, 1024, 0, ldc, qs, vrel, vt, 0);
}

// ---------------- MFMA flash attention (bf16 in/out), no-max variant -----------
__global__ __launch_bounds__(256) void attn_mfma(
    const unsigned short* __restrict__ Q, int qs,
    const unsigned short* __restrict__ K, int kvs,
    const unsigned short* __restrict__ VT,     // [(b*16+h)*64+d][1024], pos-permuted
    const float* __restrict__ maskf,           // [b][1024]
    unsigned short* __restrict__ O)
{
    __shared__ __align__(16) unsigned short Ks[64 * 64];   // [key][d]
    __shared__ __align__(16) unsigned short Vt[64 * 64];   // [d][pos]
    __shared__ __align__(16) unsigned short Pb[128 * 64];  // [q][pos]

    const int tid = threadIdx.x;
    const int b = blockIdx.z, h = blockIdx.y, q0 = blockIdx.x * 128;
    const int w = tid >> 6, lane = tid & 63;
    const int lr = lane & 15, quad = lane >> 4;
    const int wm = w * 32;
    const float4v zf = {0.f, 0.f, 0.f, 0.f};

    bf16x8 qf[2][2];
#pragma unroll
    for (int i = 0; i < 2; i++)
#pragma unroll
        for (int c = 0; c < 2; c++)
            qf[i][c] = ldsv8(Q + (size_t)(b * 1024 + q0 + wm + i * 16 + lr) * qs
                             + h * 64 + c * 32 + quad * 8);

    const int sr = lane >> 3, sc = lane & 7;
    const int fch = sc ^ sr;
    const int ch0 = quad ^ (lr & 7), ch1 = (4 + quad) ^ (lr & 7);
    const unsigned short* VTb = VT + (size_t)(b * 16 + h) * 64 * 1024;

    float4v oac[2][4];
    float lsum[2][4];
#pragma unroll
    for (int i = 0; i < 2; i++) {
#pragma unroll
        for (int j = 0; j < 4; j++) oac[i][j] = zf;
#pragma unroll
        for (int rr = 0; rr < 4; rr++) lsum[i][rr] = 0.f;
    }

    for (int kb = 0; kb < 16; ++kb) {
        const int s0 = kb * 64;
        __syncthreads();   // prev iter's Ks/Vt reads done
#pragma unroll
        for (int i = 0; i < 2; i++) {
            async16(K + (size_t)(b * 1024 + s0 + w * 16 + i * 8 + sr) * kvs + h * 64 + fch * 8,
                    &Ks[(w * 16 + i * 8) * 64]);
            async16(VTb + (size_t)(w * 16 + i * 8 + sr) * 1024 + s0 + fch * 8,
                    &Vt[(w * 16 + i * 8) * 64]);
        }
        float mf[4];
#pragma unroll
        for (int j = 0; j < 4; j++)
            mf[j] = maskf[b * 1024 + s0 + j * 16 + lr];
        __syncthreads();

        // ---- QK^T: 32 q-rows x 64 keys per wave ----
        float4v sa[2][4];
#pragma unroll
        for (int j = 0; j < 4; j++) {
            const int krow = j * 16 + lr;
            bf16x8 kf0 = ldsv8(&Ks[krow * 64 + ch0 * 8]);
            bf16x8 kf1 = ldsv8(&Ks[krow * 64 + ch1 * 8]);
            sa[0][j] = __builtin_amdgcn_mfma_f32_16x16x32_bf16(qf[0][0], kf0, zf, 0, 0, 0);
            sa[0][j] = __builtin_amdgcn_mfma_f32_16x16x32_bf16(qf[0][1], kf1, sa[0][j], 0, 0, 0);
            sa[1][j] = __builtin_amdgcn_mfma_f32_16x16x32_bf16(qf[1][0], kf0, zf, 0, 0, 0);
            sa[1][j] = __builtin_amdgcn_mfma_f32_16x16x32_bf16(qf[1][1], kf1, sa[1][j], 0, 0, 0);
        }

        // ---- p = exp(s) * mask; lane-local l partials; packed b64 P stores ----
#pragma unroll
        for (int i = 0; i < 2; i++) {
#pragma unroll
            for (int rr = 0; rr < 4; rr++) {
                const float p0 = __expf(sa[i][0][rr]) * mf[0];
                const float p1 = __expf(sa[i][1][rr]) * mf[1];
                const float p2 = __expf(sa[i][2][rr]) * mf[2];
                const float p3 = __expf(sa[i][3][rr]) * mf[3];
                lsum[i][rr] += (p0 + p1) + (p2 + p3);
                const int row = wm + i * 16 + quad * 4 + rr;
                const int schp = (lr >> 1) ^ (row & 7);
                uint2v pk = { f2bf2(p0, p1), f2bf2(p2, p3) };
                *(uint2v*)&Pb[row * 64 + schp * 8 + (lr & 1) * 4] = pk;
            }
        }
        // Pb rows of this wave written & read by the same wave -> no barrier

        // ---- PV: O += P @ V (both in permuted-key pos order) ----
        bf16x8 pf[2][2];
#pragma unroll
        for (int i = 0; i < 2; i++)
#pragma unroll
            for (int c = 0; c < 2; c++)
                pf[i][c] = ldsv8(&Pb[(wm + i * 16 + lr) * 64 + (c ? ch1 : ch0) * 8]);
#pragma unroll
        for (int j = 0; j < 4; j++) {
            bf16x8 vf0 = ldsv8(&Vt[(j * 16 + lr) * 64 + ch0 * 8]);
            bf16x8 vf1 = ldsv8(&Vt[(j * 16 + lr) * 64 + ch1 * 8]);
            oac[0][j] = __builtin_amdgcn_mfma_f32_16x16x32_bf16(pf[0][0], vf0, oac[0][j], 0, 0, 0);
            oac[0][j] = __builtin_amdgcn_mfma_f32_16x16x32_bf16(pf[0][1], vf1, oac[0][j], 0, 0, 0);
            oac[1][j] = __builtin_amdgcn_mfma_f32_16x16x32_bf16(pf[1][0], vf0, oac[1][j], 0, 0, 0);
            oac[1][j] = __builtin_amdgcn_mfma_f32_16x16x32_bf16(pf[1][1], vf1, oac[1][j], 0, 0, 0);
        }
    }

    // ---- epilogue: reduce l across the row's 16 lanes, divide, store ----
#pragma unroll
    for (int i = 0; i < 2; i++)
#pragma unroll
        for (int rr = 0; rr < 4; rr++) {
            float l = lsum[i][rr];
            l += __shfl_xor(l, 1);
            l += __shfl_xor(l, 2);
            l += __shfl_xor(l, 4);
            l += __shfl_xor(l, 8);
            const float inv = 1.0f / l;
            const int row = q0 + wm + i * 16 + quad * 4 + rr;
            unsigned short* op = O + (size_t)(b * 1024 + row) * 1024 + h * 64;
#pragma unroll
            for (int j = 0; j < 4; j++)
                op[j * 16 + lr] = f2bf1(oac[i][j][rr] * inv);
        }
}

// ------------- fused partial-sum(bf16) + bias + residual-add + LayerNorm --------
#define PSTRIDE ((size_t)4096 * 1024)
__global__ __launch_bounds__(256) void add_ln_kernel(
    const unsigned short* __restrict__ P, int nparts, const float* __restrict__ lbias,
    const float* __restrict__ R,
    const float* __restrict__ g, const float* __restrict__ bb,
    float* __restrict__ outF, unsigned short* __restrict__ outB)
{
    const int row = blockIdx.x, tid = threadIdx.x;
    float4v z = ((const float4v*)(R + (size_t)row * 1024))[tid];
    for (int p = 0; p < nparts; ++p)
        z += bf4_to_f4(*(const uint2v*)(P + p * PSTRIDE + (size_t)row * 1024 + tid * 4));
    if (lbias) z += ((const float4v*)lbias)[tid];
    float s = z.x + z.y + z.z + z.w;
    float sq = z.x * z.x + z.y * z.y + z.z * z.z + z.w * z.w;
#pragma unroll
    for (int off = 32; off > 0; off >>= 1) {
        s += __shfl_down(s, off);
        sq += __shfl_down(sq, off);
    }
    __shared__ float ws[4], wsq[4];
    __shared__ float sm, sr;
    if ((tid & 63) == 0) { ws[tid >> 6] = s; wsq[tid >> 6] = sq; }
    __syncthreads();
    if (tid == 0) {
        float S1 = ws[0] + ws[1] + ws[2] + ws[3];
        float S2 = wsq[0] + wsq[1] + wsq[2] + wsq[3];
        float mean = S1 * (1.0f / 1024.0f);
        float var = S2 * (1.0f / 1024.0f) - mean * mean;
        sm = mean;
        sr = rsqrtf(var + 1e-5f);
    }
    __syncthreads();
    const float mean = sm, rstd = sr;
    const float4v* g4 = (const float4v*)g;
    const float4v* b4 = (const float4v*)bb;
    float4v res = g4[tid] * ((z - mean) * rstd) + b4[tid];
    if (outF) ((float4v*)(outF + (size_t)row * 1024))[tid] = res;
    if (outB) {
        uint2v u = { f2bf2(res.x, res.y), f2bf2(res.z, res.w) };
        *(uint2v*)(outB + (size_t)row * 1024 + tid * 4) = u;
    }
}

// ---------------- transpose + convert body: S[R][C] f32 -> D[C][R] bf16 ---------
__device__ __forceinline__ void tconv_body(const float* __restrict__ S,
                                           unsigned short* __restrict__ D,
                                           int R, int C, int r0, int c0)
{
    __shared__ float tile[64][65];
    const int tid = threadIdx.x;
    const int tr = tid >> 4, tc4 = (tid & 15) * 4;
#pragma unroll
    for (int i = 0; i < 4; i++) {
        const int rr = i * 16 + tr;
        *(float4v*)&tile[rr][tc4] = *(const float4v*)(S + (size_t)(r0 + rr) * C + c0 + tc4);
    }
    __syncthreads();
#pragma unroll
    for (int i = 0; i < 4; i++) {
        const int dr = i * 16 + tr;   // dst row = src col
        float v0 = tile[tc4 + 0][dr];
        float v1 = tile[tc4 + 1][dr];
        float v2 = tile[tc4 + 2][dr];
        float v3 = tile[tc4 + 3][dr];
        uint2v u = { f2bf2(v0, v1), f2bf2(v2, v3) };
        *(uint2v*)(D + (size_t)(c0 + dr) * R + r0 + tc4) = u;
    }
}

// ---------------- single fused prep kernel --------------------------------------
// blocks [0,8192): x/cx f32->bf16; [8192,10240): 8 square 1024^2 transposes;
// [10240,11264): W1^T; [11264,12288): W2^T; [12288,12340): biases+masks.
__global__ __launch_bounds__(256) void prep_all(
    const float* __restrict__ x, const float* __restrict__ cx,
    unsigned short* __restrict__ xb, unsigned short* __restrict__ cxb,
    const float* s0, const float* s1, const float* s2, const float* s3,
    const float* s4, const float* s5, const float* s6, const float* s7,
    unsigned short* d0, unsigned short* d1, unsigned short* d2, unsigned short* d3,
    unsigned short* d4, unsigned short* d5, unsigned short* d6, unsigned short* d7,
    const float* __restrict__ W1, unsigned short* __restrict__ WtW1,
    const float* __restrict__ W2, unsigned short* __restrict__ WtW2,
    const float* __restrict__ sbq, const float* __restrict__ sbk, const float* __restrict__ sbv,
    const float* __restrict__ cbk, const float* __restrict__ cbv,
    const int* __restrict__ smask, const int* __restrict__ cmask,
    float* __restrict__ bq, float* __restrict__ bc,
    float* __restrict__ smf, float* __restrict__ cmf)
{
    const int bid = blockIdx.x, tid = threadIdx.x;
    if (bid < 8192) {
        const float* s = bid < 4096 ? x : cx;
        unsigned short* d = bid < 4096 ? xb : cxb;
        const size_t i = ((size_t)(bid & 4095) * 256 + tid) * 4;
        float4v v = *(const float4v*)(s + i);
        uint2v u = { f2bf2(v.x, v.y), f2bf2(v.z, v.w) };
        *(uint2v*)(d + i) = u;
    } else if (bid < 10240) {
        const int t = bid - 8192;
        const int which = t >> 8, sub = t & 255;
        const float* S;
        unsigned short* D;
        switch (which) {
            case 0: S = s0; D = d0; break;
            case 1: S = s1; D = d1; break;
            case 2: S = s2; D = d2; break;
            case 3: S = s3; D = d3; break;
            case 4: S = s4; D = d4; break;
            case 5: S = s5; D = d5; break;
            case 6: S = s6; D = d6; break;
            default: S = s7; D = d7; break;
        }
        tconv_body(S, D, 1024, 1024, (sub >> 4) * 64, (sub & 15) * 64);
    } else if (bid < 11264) {
        const int t = bid - 10240;           // W1: R=1024, C=4096
        tconv_body(W1, WtW1, 1024, 4096, (t >> 6) * 64, (t & 63) * 64);
    } else if (bid < 12288) {
        const int t = bid - 11264;           // W2: R=4096, C=1024
        tconv_body(W2, WtW2, 4096, 1024, (t & 63) * 64, (t >> 6) * 64);
    } else {
        const int i = (bid - 12288) * 256 + tid;
        if (i < 3072)
            bq[i] = i < 1024 ? sbq[i] : (i < 2048 ? sbk[i - 1024] : sbv[i - 2048]);
        else if (i < 5120) {
            const int j = i - 3072;
            bc[j] = j < 1024 ? cbk[j] : cbv[j - 1024];
        } else if (i < 9216)
            smf[i - 5120] = (float)smask[i - 5120];
        else
            cmf[i - 9216] = (float)cmask[i - 9216];
    }
}

// --------------------------------------------------------------------------------
extern "C" void kernel_launch(void* const* d_in, const int* in_sizes, int n_in,
                              void* d_out, int out_size, void* d_ws, size_t ws_size,
                              hipStream_t stream)
{
    const float* x     = (const float*)d_in[0];
    const int*   smask = (const int*)d_in[1];
    const float* cx    = (const float*)d_in[2];
    const int*   cmask = (const int*)d_in[3];
    const float* sWq = (const float*)d_in[5],  *sbq = (const float*)d_in[6];
    const float* sWk = (const float*)d_in[7],  *sbk = (const float*)d_in[8];
    const float* sWv = (const float*)d_in[9],  *sbv = (const float*)d_in[10];
    const float* sWo = (const float*)d_in[11], *sbo = (const float*)d_in[12];
    const float* cWq = (const float*)d_in[13], *cbq = (const float*)d_in[14];
    const float* cWk = (const float*)d_in[15], *cbk = (const float*)d_in[16];
    const float* cWv = (const float*)d_in[17], *cbv = (const float*)d_in[18];
    const float* cWo = (const float*)d_in[19], *cbo = (const float*)d_in[20];
    const float* g   = (const float*)d_in[21], *bb  = (const float*)d_in[22];
    const float* W1  = (const float*)d_in[23], *b1  = (const float*)d_in[24];
    const float* W2  = (const float*)d_in[25], *b2  = (const float*)d_in[26];
    float* out = (float*)d_out;

    const size_t MB = 1024 * 1024;
    unsigned char* ws = (unsigned char*)d_ws;
    unsigned short* xb   = (unsigned short*)(ws + 0 * MB);    // 8 MB
    unsigned short* cxb  = (unsigned short*)(ws + 8 * MB);    // 8 MB
    unsigned short* SANb = (unsigned short*)(ws + 16 * MB);   // 8 MB
    unsigned short* CQ   = (unsigned short*)(ws + 24 * MB);   // 8 MB
    unsigned short* MID  = (unsigned short*)(ws + 0 * MB);    // 32 MB (FFN; xb..CQ dead)
    unsigned short* QK   = (unsigned short*)(ws + 32 * MB);   // 16 MB [4096][2048]
    unsigned short* VTs  = (unsigned short*)(ws + 48 * MB);   // 8 MB [(b,h,d)][1024]
    unsigned short* P    = (unsigned short*)(ws + 32 * MB);   // 2x8 MB bf16 partials
    unsigned short* CKb  = (unsigned short*)(ws + 56 * MB);   // 8 MB [4096][1024]
    unsigned short* VTc  = (unsigned short*)(ws + 64 * MB);   // 8 MB
    unsigned short* T    = (unsigned short*)(ws + 72 * MB);   // 8 MB
    float*          HH   = (float*)(ws + 80 * MB);            // 16 MB
    unsigned short* HHb  = (unsigned short*)(ws + 96 * MB);   // 8 MB
    unsigned short* WtQKV = (unsigned short*)(ws + 104 * MB); // 6 MB [3072][1024]
    unsigned short* WtCKV = (unsigned short*)(ws + 110 * MB); // 4 MB [2048][1024]
    unsigned short* WtSWO = (unsigned short*)(ws + 114 * MB); // 2 MB
    unsigned short* WtCWQ = (unsigned short*)(ws + 116 * MB); // 2 MB
    unsigned short* WtCWO = (unsigned short*)(ws + 118 * MB); // 2 MB
    unsigned short* WtW1  = (unsigned short*)(ws + 120 * MB); // 8 MB
    unsigned short* WtW2  = (unsigned short*)(ws + 128 * MB); // 8 MB
    float* biasQ = (float*)(ws + 136 * MB);                   // 12 KB
    float* biasC = (float*)(ws + 136 * MB + 16 * 1024);       // 8 KB
    float* smf   = (float*)(ws + 136 * MB + 32 * 1024);       // 16 KB
    float* cmf   = (float*)(ws + 136 * MB + 48 * 1024);       // 16 KB

    dim3 blk(256);

    // ---- all prep in one launch ----
    prep_all<<<12340, blk, 0, stream>>>(
        x, cx, xb, cxb,
        sWq, sWk, sWv, cWk, cWv, sWo, cWq, cWo,
        WtQKV, WtQKV + 1024 * 1024, WtQKV + 2 * 1024 * 1024,
        WtCKV, WtCKV + 1024 * 1024,
        WtSWO, WtCWQ, WtCWO,
        W1, WtW1, W2, WtW2,
        sbq, sbk, sbv, cbk, cbv, smask, cmask, biasQ, biasC, smf, cmf);

    // ---- self QKV + cross K/V in one launch (both depend only on prep) ----
    gemm_qkv_ckv<<<dim3(32, 40), blk, 0, stream>>>(
        xb, WtQKV, biasQ, QK, VTs, cxb, WtCKV, biasC, CKb, VTc);
    attn_mfma<<<dim3(8, 16, 4), blk, 0, stream>>>(QK, 2048, QK + 1024, 2048, VTs, smf, T);
    gemm_bt<0, 1><<<dim3(32, 8, 2), blk, 0, stream>>>(
        T, WtSWO, nullptr, P, 4096, 1024, 1024, 1024, 1, 0, VBIG, nullptr);
    add_ln_kernel<<<4096, blk, 0, stream>>>(P, 2, sbo, x, g, bb, nullptr, SANb);

    // ---- cross attention (residual = ORIGINAL x); K/V already done ----
    gemm_bt<0, 0><<<dim3(32, 8), blk, 0, stream>>>(
        SANb, WtCWQ, cbq, CQ, 4096, 1024, 1024, 1024, 1, 1024, VBIG, nullptr);
    attn_mfma<<<dim3(8, 16, 4), blk, 0, stream>>>(CQ, 1024, CKb, 1024, VTc, cmf, T);
    gemm_bt<0, 1><<<dim3(32, 8, 2), blk, 0, stream>>>(
        T, WtCWO, nullptr, P, 4096, 1024, 1024, 1024, 1, 0, VBIG, nullptr);
    add_ln_kernel<<<4096, blk, 0, stream>>>(P, 2, cbo, x, g, bb, HH, HHb);

    // ---- FFN ----
    gemm_bt<1, 0><<<dim3(32, 32), blk, 0, stream>>>(
        HHb, WtW1, b1, MID, 4096, 4096, 1024, 4096, 0, 0, VBIG, nullptr);
    gemm_bt<0, 1><<<dim3(32, 8, 2), blk, 0, stream>>>(
        MID, WtW2, nullptr, P, 4096, 1024, 4096, 1024, 1, 0, VBIG, nullptr);
    add_ln_kernel<<<4096, blk, 0, stream>>>(P, 2, b2, HH, g, bb, out, nullptr);
}